// Round 15
// baseline (710.619 us; speedup 1.0000x reference)
//
#include <hip/hip_runtime.h>
#include <hip/hip_bf16.h>
#include <math.h>

#define N_NODES  100000
#define N_EDGES  1600000
#define N_GRAPHS 4096
#define NBUCKET  ((N_NODES + 127) / 128)   // 782
#define NPART    256
#define ROWBLKS_AL 6256                    // padded 16-row blocks for OOB-safe frag reads

typedef __attribute__((ext_vector_type(4))) float f32x4;
typedef __attribute__((ext_vector_type(8))) short bf16x8;

__device__ __forceinline__ float lrelu(float x) { return fmaxf(x, 0.01f * x); }

__device__ __forceinline__ unsigned short f2bf(float f) {
    unsigned u = __float_as_uint(f);
    unsigned r = (u + 0x7FFFu + ((u >> 16) & 1u)) >> 16;
    return (unsigned short)r;
}
__device__ __forceinline__ float bf2f(unsigned short h) {
    return __uint_as_float(((unsigned)h) << 16);
}

// ------- exclusive scan, single block 1024 thr, shuffle-based --------------
__global__ __launch_bounds__(1024) void scan_kernel(const unsigned* __restrict__ in,
                                                    unsigned* __restrict__ out, int n) {
    __shared__ unsigned wsum[16];
    __shared__ unsigned carry_s;
    int t = threadIdx.x, lane = t & 63, wv = t >> 6;
    if (t == 0) carry_s = 0u;
    __syncthreads();
    for (int base = 0; base < n; base += 4096) {
        unsigned carry = carry_s;
        unsigned v[4]; unsigned s = 0u;
#pragma unroll
        for (int i = 0; i < 4; ++i) {
            int idx = base + t * 4 + i;
            v[i] = (idx < n) ? in[idx] : 0u;
            s += v[i];
        }
        unsigned ps = s;
#pragma unroll
        for (int off = 1; off < 64; off <<= 1) {
            unsigned x = __shfl_up(ps, off, 64);
            if (lane >= off) ps += x;
        }
        if (lane == 63) wsum[wv] = ps;
        __syncthreads();
        if (wv == 0 && lane < 16) {
            unsigned pw = wsum[lane];
#pragma unroll
            for (int off = 1; off < 16; off <<= 1) {
                unsigned x = __shfl_up(pw, off, 64);
                if (lane >= off) pw += x;
            }
            wsum[lane] = pw;
        }
        __syncthreads();
        unsigned wbase = wv ? wsum[wv - 1] : 0u;
        unsigned run = carry + wbase + (ps - s);
#pragma unroll
        for (int i = 0; i < 4; ++i) {
            int idx = base + t * 4 + i;
            if (idx < n) out[idx] = run;
            run += v[i];
        }
        unsigned total = wsum[15];
        __syncthreads();
        if (t == 0) carry_s = carry + total;
        __syncthreads();
    }
    if (t == 0) out[n] = carry_s;
}

// ---- CSR pass 1: per-partition bucket histogram (LDS only) ----------------
__global__ __launch_bounds__(256) void phist_kernel(const int* __restrict__ dst,
        unsigned* __restrict__ cnt, int E, int chunk) {
    __shared__ unsigned lc[NBUCKET];
    int p = blockIdx.x, t = threadIdx.x;
    for (int i = t; i < NBUCKET; i += 256) lc[i] = 0u;
    __syncthreads();
    int e0 = p * chunk, e1 = e0 + chunk; if (e1 > E) e1 = E;
    for (int e = e0 + t; e < e1; e += 256)
        atomicAdd(&lc[((unsigned)dst[e]) >> 7], 1u);
    __syncthreads();
    for (int i = t; i < NBUCKET; i += 256) cnt[(size_t)p * NBUCKET + i] = lc[i];
}

// ---- CSR pass 1b: bucket totals (column sums of cnt[p][b]) ----------------
__global__ void btot_kernel(const unsigned* __restrict__ cnt, unsigned* __restrict__ tot) {
    int b = blockIdx.x * 256 + threadIdx.x;
    if (b >= NBUCKET) return;
    unsigned s = 0u;
    for (int p = 0; p < NPART; ++p) s += cnt[(size_t)p * NBUCKET + b];
    tot[b] = s;
}

// ---- CSR pass 2a: per-bucket exclusive scan over partitions ---------------
__global__ __launch_bounds__(256) void poff_kernel(unsigned* __restrict__ cnt,
        const unsigned* __restrict__ bucket_base) {
    int b = blockIdx.x * 4 + (threadIdx.x >> 6);
    if (b >= NBUCKET) return;
    int lane = threadIdx.x & 63;
    unsigned v[4]; unsigned s = 0u;
#pragma unroll
    for (int i = 0; i < 4; ++i) {
        int p = lane * 4 + i;
        v[i] = cnt[(size_t)p * NBUCKET + b];
        s += v[i];
    }
    unsigned ps = s;
#pragma unroll
    for (int off = 1; off < 64; off <<= 1) {
        unsigned x = __shfl_up(ps, off, 64);
        if (lane >= off) ps += x;
    }
    unsigned run = bucket_base[b] + (ps - s);
#pragma unroll
    for (int i = 0; i < 4; ++i) {
        int p = lane * 4 + i;
        cnt[(size_t)p * NBUCKET + b] = run;
        run += v[i];
    }
}

// ---- CSR pass 2b: scatter packed (src | dstLow<<20), LDS cursors ----------
__global__ __launch_bounds__(256) void pscat_kernel(const int* __restrict__ ei,
        const unsigned* __restrict__ cnt, unsigned* __restrict__ pair, int E, int chunk) {
    __shared__ unsigned lcur[NBUCKET];
    int p = blockIdx.x, t = threadIdx.x;
    for (int i = t; i < NBUCKET; i += 256) lcur[i] = cnt[(size_t)p * NBUCKET + i];
    __syncthreads();
    int e0 = p * chunk, e1 = e0 + chunk; if (e1 > E) e1 = E;
    for (int e = e0 + t; e < e1; e += 256) {
        unsigned src = (unsigned)ei[e];
        unsigned dst = (unsigned)ei[E + e];
        unsigned b = dst >> 7;
        unsigned pos = atomicAdd(&lcur[b], 1u);
        pair[pos] = src | ((dst & 127u) << 20);
    }
}

// ---- CSR pass 3: per-bucket degree count + LDS scan -> row_ptr, fine sort -> col
__global__ __launch_bounds__(256) void fillc2_kernel(const unsigned* __restrict__ pair,
        const unsigned* __restrict__ bucket_base, unsigned* __restrict__ row_ptr,
        unsigned* __restrict__ col, int N) {
    __shared__ unsigned lcnt[128], lpre[128], lcur[128];
    int b = blockIdx.x;
    int node0 = b << 7;
    int t = threadIdx.x;
    if (t < 128) { lcnt[t] = 0u; lcur[t] = 0u; }
    __syncthreads();
    unsigned bb = bucket_base[b], be = bucket_base[b + 1];
    for (unsigned i = bb + t; i < be; i += 256)
        atomicAdd(&lcnt[(pair[i] >> 20) & 127u], 1u);
    __syncthreads();
    if (t < 64) {
        unsigned v0 = lcnt[2 * t], v1 = lcnt[2 * t + 1];
        unsigned s = v0 + v1;
        unsigned ps = s;
#pragma unroll
        for (int off = 1; off < 64; off <<= 1) {
            unsigned x = __shfl_up(ps, off, 64);
            if (t >= off) ps += x;
        }
        unsigned base = ps - s;
        lpre[2 * t] = base;
        lpre[2 * t + 1] = base + v0;
    }
    __syncthreads();
    if (t < 128) {
        int node = node0 + t;
        if (node < N) row_ptr[node] = bb + lpre[t];
    }
    if (b == (int)gridDim.x - 1 && t == 0) row_ptr[N] = be;
    for (unsigned i = bb + t; i < be; i += 256) {
        unsigned u = pair[i];
        unsigned d = (u >> 20) & 127u;
        unsigned pos = bb + lpre[d] + atomicAdd(&lcur[d], 1u);
        col[pos] = u & 0xFFFFFu;
    }
}

// ---- graph segmentation: batch is sorted -> binary search per boundary ----
__global__ void gsearch_kernel(const int* __restrict__ batch, unsigned* __restrict__ gptr,
                               int N, int G) {
    int g = blockIdx.x * 256 + threadIdx.x;
    if (g > G) return;
    int lo = 0, hi = N;
    while (lo < hi) { int mid = (lo + hi) >> 1; if (batch[mid] < g) lo = mid + 1; else hi = mid; }
    gptr[g] = (unsigned)lo;
}

// ---------------- cast x (f32) -> bf16 shadow, x4 vectorized ---------------
__global__ void cast_kernel(const float* __restrict__ in, unsigned short* __restrict__ outb, int n4) {
    int i = blockIdx.x * 256 + threadIdx.x;
    if (i >= n4) return;
    f32x4 v = *(const f32x4*)(in + (size_t)i * 4);
    uint2 u;
    u.x = (unsigned)f2bf(v[0]) | ((unsigned)f2bf(v[1]) << 16);
    u.y = (unsigned)f2bf(v[2]) | ((unsigned)f2bf(v[3]) << 16);
    *(uint2*)(outb + (size_t)i * 4) = u;
}

// ---- transform pass: y = lrelu(a*h + d), affine from stats (LDS) ---------
__global__ __launch_bounds__(256) void tfm_kernel(const unsigned short* __restrict__ hb,
        const float* __restrict__ stats, const float* __restrict__ wp,
        const float* __restrict__ bp, const float* __restrict__ sp, float invN,
        unsigned short* __restrict__ yb, int total8) {
    __shared__ float la[128], ldd[128];
    int t = threadIdx.x;
    if (t < 128) {
        float mean = stats[t] * invN;
        float ex2  = stats[128 + t] * invN;
        float sv   = sp[t];
        float var  = ex2 - 2.f * sv * mean * mean + sv * sv * mean * mean;
        float a    = wp[t] * rsqrtf(var + 1e-5f);
        la[t] = a; ldd[t] = bp[t] - a * sv * mean;
    }
    __syncthreads();
    int i = blockIdx.x * 256 + t;
    if (i >= total8) return;
    int c0 = (i & 15) * 8;
    uint4 u = *(const uint4*)(hb + (size_t)i * 8);
    unsigned uu[4] = {u.x, u.y, u.z, u.w};
    unsigned ow[4];
#pragma unroll
    for (int q = 0; q < 4; ++q) {
        int c = c0 + 2 * q;
        float v0 = lrelu(fmaf(la[c],     __uint_as_float(uu[q] << 16),         ldd[c]));
        float v1 = lrelu(fmaf(la[c + 1], __uint_as_float(uu[q] & 0xffff0000u), ldd[c + 1]));
        ow[q] = (unsigned)f2bf(v0) | ((unsigned)f2bf(v1) << 16);
    }
    uint4 o; o.x = ow[0]; o.y = ow[1]; o.z = ow[2]; o.w = ow[3];
    *(uint4*)(yb + (size_t)i * 8) = o;
}

// ---------------- aggregation: m[n] = y[n] + sum_{j in N(n)} y[j] ----------
// pure sum; one wave per node; 8-deep edge unroll; frag-linear output.
template<int D, int KOCT>
__global__ __launch_bounds__(256) void agg_kernel(const unsigned short* __restrict__ hb, int ld_in,
        const unsigned* __restrict__ row_ptr, const unsigned* __restrict__ col,
        unsigned short* __restrict__ op, int n) {
    int node = blockIdx.x * 4 + (threadIdx.x >> 6);
    int l = threadIdx.x & 63;
    if (node >= n || l >= KOCT * 4) return;
    int c = 2 * l;
    float x0 = 0.f, x1 = 0.f;
    if (c < D) {
        const unsigned short* hp = hb + c;
#define LOADU(s) *(const unsigned*)(hp + (size_t)(s) * ld_in)
#define LO(u) __uint_as_float((u) << 16)
#define HI(u) __uint_as_float((u) & 0xffff0000u)
        unsigned su = LOADU(node);
        x0 = LO(su); x1 = HI(su);
        float y0 = 0.f, y1 = 0.f, z0 = 0.f, z1 = 0.f, q0 = 0.f, q1 = 0.f;
        unsigned e0 = row_ptr[node], e1 = row_ptr[node + 1];
        unsigned e = e0;
        for (; e + 8 <= e1; e += 8) {
            unsigned c0i = col[e],     c1i = col[e + 1], c2i = col[e + 2], c3i = col[e + 3];
            unsigned c4i = col[e + 4], c5i = col[e + 5], c6i = col[e + 6], c7i = col[e + 7];
            unsigned u0 = LOADU(c0i), u1 = LOADU(c1i), u2 = LOADU(c2i), u3 = LOADU(c3i);
            unsigned u4 = LOADU(c4i), u5 = LOADU(c5i), u6 = LOADU(c6i), u7 = LOADU(c7i);
            x0 += LO(u0); x1 += HI(u0); y0 += LO(u1); y1 += HI(u1);
            z0 += LO(u2); z1 += HI(u2); q0 += LO(u3); q1 += HI(u3);
            x0 += LO(u4); x1 += HI(u4); y0 += LO(u5); y1 += HI(u5);
            z0 += LO(u6); z1 += HI(u6); q0 += LO(u7); q1 += HI(u7);
        }
        for (; e + 4 <= e1; e += 4) {
            unsigned c0i = col[e], c1i = col[e + 1], c2i = col[e + 2], c3i = col[e + 3];
            unsigned u0 = LOADU(c0i), u1 = LOADU(c1i), u2 = LOADU(c2i), u3 = LOADU(c3i);
            x0 += LO(u0); x1 += HI(u0); y0 += LO(u1); y1 += HI(u1);
            z0 += LO(u2); z1 += HI(u2); q0 += LO(u3); q1 += HI(u3);
        }
        for (; e < e1; ++e) {
            unsigned u = LOADU(col[e]);
            x0 += LO(u); x1 += HI(u);
        }
#undef LOADU
#undef LO
#undef HI
        x0 = (x0 + y0) + (z0 + q0);
        x1 = (x1 + y1) + (z1 + q1);
    }
    unsigned outw = (unsigned)f2bf(x0) | ((unsigned)f2bf(x1) << 16);
    size_t fo = (((size_t)(node >> 4) * KOCT + (l >> 2)) * 16 + (node & 15)) * 8 + 2 * (l & 3);
    *(unsigned*)(op + fo) = outw;
}

// ---- W preprocess: hi/lo bf16 split into FRAGMENT-LINEAR order -----------
__global__ __launch_bounds__(256) void wsplit_kernel(const float* __restrict__ W1_0,
        const float* __restrict__ W1_rest, const float* __restrict__ W2,
        unsigned short* __restrict__ wt) {
    int g = blockIdx.y;
    int i = blockIdx.x * 256 + threadIdx.x;   // i < 32768
    int e = i & 7, lane = (i >> 3) & 63, h = (i >> 9) & 1, j = (i >> 10) & 7, ks = i >> 13;
    int m = lane & 15, kg = lane >> 4;
    int k = ks * 32 + kg * 8 + e;
    int n = 8 * m + j;
    float v = 0.f;
    if (g == 0) { if (k < 48) v = W1_0[k * 128 + n]; }
    else if (g & 1) v = W2[(size_t)((g - 1) >> 1) * 16384 + k * 128 + n];
    else            v = W1_rest[(size_t)((g - 2) >> 1) * 16384 + k * 128 + n];
    unsigned short hi = f2bf(v);
    unsigned short out = (h == 0) ? hi : f2bf(v - bf2f(hi));
    wt[(size_t)g * 32768 + i] = out;
}

// ---------------- MFMA GEMM v9 -------------------------------------------
// block = 4 waves (2x2): wave = 96 rows (6 rowgroups) x 64 cols; block = 192
// rows x 128 cols; grid = ceil(N/192) = 521 (~1 concurrent round at 2/CU).
// Full W (hi+lo, frag-linear) staged in 64KB LDS once per block: per-wave W
// traffic becomes ds_read; only A-loads (24, independent) hit global.
// Stats LDS aliases the W buffer after the main loop (64KB static total).
template<int KS, int KOCT, bool AFF, bool STATS, bool BF16OUT, bool FRAGOUT>
__global__ __launch_bounds__(256, 2) void mgemm_kernel(
        const unsigned short* __restrict__ Ah,
        const float* __restrict__ stats, const float* __restrict__ wp,
        const float* __restrict__ bp, const float* __restrict__ sp, float invN,
        const unsigned short* __restrict__ Wt, const float* __restrict__ bias,
        unsigned short* __restrict__ outb, unsigned short* __restrict__ ofh,
        float* __restrict__ ostats, int M) {
    __shared__ unsigned short wlds[32768];   // 64KB: full W hi/lo frag-linear
    int t = threadIdx.x;
    constexpr int WTOT = KS * 8192;          // shorts actually used
    for (int i = t * 8; i < WTOT; i += 256 * 8)
        *(uint4*)(wlds + i) = *(const uint4*)(Wt + i);
    __syncthreads();

    int lane = t & 63;
    int m = lane & 15, kg = lane >> 4;
    int wid = t >> 6;
    int wr = wid >> 1, wc = wid & 1;
    int rowBase = blockIdx.x * 192 + wr * 96;
    int rowblk0 = blockIdx.x * 12 + wr * 6;

    union U8 { bf16x8 v; unsigned short u[8]; };

    f32x4 acc[6][4];
#pragma unroll
    for (int j = 0; j < 4; ++j) {
        float b = bias[8 * m + wc * 4 + j];
#pragma unroll
        for (int rg = 0; rg < 6; ++rg) acc[rg][j] = (f32x4){b, b, b, b};
    }

#pragma unroll
    for (int ks = 0; ks < KS; ++ks) {
        int k0 = ks * 32 + kg * 8;
        float aC[8], dC[8];
        if (AFF) {
            f32x4 sm0 = *(const f32x4*)(stats + k0),       sm1 = *(const f32x4*)(stats + k0 + 4);
            f32x4 se0 = *(const f32x4*)(stats + 128 + k0), se1 = *(const f32x4*)(stats + 128 + k0 + 4);
            f32x4 w0  = *(const f32x4*)(wp + k0),          w1  = *(const f32x4*)(wp + k0 + 4);
            f32x4 b0  = *(const f32x4*)(bp + k0),          b1  = *(const f32x4*)(bp + k0 + 4);
            f32x4 s0  = *(const f32x4*)(sp + k0),          s1  = *(const f32x4*)(sp + k0 + 4);
#pragma unroll
            for (int q = 0; q < 8; ++q) {
                float mean = (q < 4 ? sm0[q] : sm1[q - 4]) * invN;
                float ex2  = (q < 4 ? se0[q] : se1[q - 4]) * invN;
                float sv   = (q < 4 ? s0[q]  : s1[q - 4]);
                float var  = ex2 - 2.f * sv * mean * mean + sv * sv * mean * mean;
                float a    = (q < 4 ? w0[q] : w1[q - 4]) * rsqrtf(var + 1e-5f);
                aC[q] = a;
                dC[q] = (q < 4 ? b0[q] : b1[q - 4]) - a * sv * mean;
            }
        }
        U8 fh[6];
#pragma unroll
        for (int rg = 0; rg < 6; ++rg) {
            size_t ao = (((size_t)(rowblk0 + rg) * KOCT + ks * 4 + kg) << 7) + (m << 3);
            U8 h;
            h.v = *(const bf16x8*)(Ah + ao);          // in-bounds by padded alloc
            if (AFF) {
#pragma unroll
                for (int q = 0; q < 8; ++q) {
                    float xv = lrelu(fmaf(aC[q], bf2f(h.u[q]), dC[q]));
                    h.u[q] = f2bf(xv);
                }
            }
            fh[rg] = h;
        }
#pragma unroll
        for (int j = 0; j < 4; ++j) {
            int wo = (ks * 8 + wc * 4 + j) * 1024 + lane * 8;
            bf16x8 whi = *(const bf16x8*)(wlds + wo);
            bf16x8 wlo = *(const bf16x8*)(wlds + wo + 512);
#pragma unroll
            for (int rg = 0; rg < 6; ++rg) {
                acc[rg][j] = __builtin_amdgcn_mfma_f32_16x16x32_bf16(fh[rg].v, whi, acc[rg][j], 0, 0, 0);
                acc[rg][j] = __builtin_amdgcn_mfma_f32_16x16x32_bf16(fh[rg].v, wlo, acc[rg][j], 0, 0, 0);
            }
        }
    }

    // epilogue: row = rowBase + rg*16 + kg*4 + r; lane's cols = 8m+wc*4 .. +3
#pragma unroll
    for (int rg = 0; rg < 6; ++rg) {
#pragma unroll
        for (int r = 0; r < 4; ++r) {
            int gr = rowBase + rg * 16 + kg * 4 + r;
            if (gr < M) {
                unsigned short h[4];
#pragma unroll
                for (int q = 0; q < 4; ++q) h[q] = f2bf(acc[rg][q][r]);
                uint2 uh;
                uh.x = (unsigned)h[0] | ((unsigned)h[1] << 16);
                uh.y = (unsigned)h[2] | ((unsigned)h[3] << 16);
                if (BF16OUT) *(uint2*)(outb + (size_t)gr * 128 + 8 * m + wc * 4) = uh;
                if (FRAGOUT) {
                    size_t fo = (((size_t)(rowblk0 + rg) * 16 + m) * 16 + (kg * 4 + r)) * 8 + wc * 4;
                    *(uint2*)(ofh + fo) = uh;
                }
            }
        }
    }

    if (STATS) {
        __syncthreads();                    // all W ds_reads complete
        float* ls = (float*)wlds;           // alias the (now dead) W buffer
        ls[t] = 0.f;
        __syncthreads();
#pragma unroll
        for (int j = 0; j < 4; ++j) {
            float s = 0.f, s2 = 0.f;
#pragma unroll
            for (int rg = 0; rg < 6; ++rg)
#pragma unroll
                for (int r = 0; r < 4; ++r) {
                    int gr = rowBase + rg * 16 + kg * 4 + r;
                    if (gr < M) { float v = acc[rg][j][r]; s += v; s2 += v * v; }
                }
            atomicAdd(&ls[8 * m + wc * 4 + j], s);
            atomicAdd(&ls[128 + 8 * m + wc * 4 + j], s2);
        }
        __syncthreads();
        atomicAdd(&ostats[t], ls[t]);
    }
}

// ------- fused pooling (mean/sum/max) + readout head, 1 wave per graph -----
__global__ __launch_bounds__(64) void poolhead_kernel(const unsigned short* __restrict__ hb,
        const unsigned* __restrict__ gptr,
        const float* __restrict__ w1, const float* __restrict__ b1,
        const float* __restrict__ w2, const float* __restrict__ b2,
        float* __restrict__ out, int G) {
    __shared__ float red[384];
    __shared__ float y[64];
    int g = blockIdx.x, t = threadIdx.x;
    unsigned s = gptr[g], e = gptr[g + 1];
    int c = 2 * t;
    float sx = 0.f, sy = 0.f, mx = -INFINITY, my = -INFINITY;
    for (unsigned n = s; n < e; ++n) {
        unsigned u = *(const unsigned*)(hb + (size_t)n * 128 + c);
        float vx = __uint_as_float(u << 16);
        float vy = __uint_as_float(u & 0xffff0000u);
        sx += vx; sy += vy;
        mx = fmaxf(mx, vx); my = fmaxf(my, vy);
    }
    float cnt = (float)(e - s);
    float inv = 1.f / fmaxf(cnt, 1.f);
    if (e == s) { mx = 0.f; my = 0.f; }
    red[c] = sx * inv;   red[c + 1] = sy * inv;
    red[128 + c] = sx;   red[129 + c] = sy;
    red[256 + c] = mx;   red[257 + c] = my;
    __syncthreads();
    float acc = b1[t];
    for (int k = 0; k < 384; ++k) acc += red[k] * w1[(size_t)k * 64 + t];
    y[t] = lrelu(acc);
    __syncthreads();
    if (t < 3) {
        float o = b2[t];
        for (int k = 0; k < 64; ++k) o += y[k] * w2[k * 3 + t];
        out[(size_t)g * 3 + t] = o;
    }
}

extern "C" void kernel_launch(void* const* d_in, const int* in_sizes, int n_in,
                              void* d_out, int out_size, void* d_ws, size_t ws_size,
                              hipStream_t stream) {
    const float* x       = (const float*)d_in[0];
    const float* W1_0    = (const float*)d_in[2];
    const float* b1_0    = (const float*)d_in[3];
    const float* W1_rest = (const float*)d_in[4];
    const float* b1_rest = (const float*)d_in[5];
    const float* gn_w    = (const float*)d_in[6];
    const float* gn_b    = (const float*)d_in[7];
    const float* gn_s    = (const float*)d_in[8];
    const float* W2      = (const float*)d_in[9];
    const float* b2      = (const float*)d_in[10];
    const float* pn_w    = (const float*)d_in[11];
    const float* pn_b    = (const float*)d_in[12];
    const float* pn_s    = (const float*)d_in[13];
    const float* fc1W    = (const float*)d_in[14];
    const float* fc1b    = (const float*)d_in[15];
    const float* fc2W    = (const float*)d_in[16];
    const float* fc2b    = (const float*)d_in[17];
    const int*   ei      = (const int*)d_in[18];
    const int*   batch   = (const int*)d_in[19];
    float* outp = (float*)d_out;

    const int N = N_NODES, E = N_EDGES, G = N_GRAPHS;
    const int CHUNK = (E + NPART - 1) / NPART;
    const size_t FRAGSZ = (size_t)ROWBLKS_AL * 16 * 128;   // shorts per frag plane
    char* w = (char*)d_ws;
    auto alloc = [&](size_t bytes) -> char* {
        char* p = w; w += (bytes + 255) & ~(size_t)255; return p;
    };
    unsigned short* p1h = (unsigned short*)alloc(FRAGSZ * 2);           // agg out (frag)
    unsigned short* p2h = (unsigned short*)alloc(FRAGSZ * 2);           // GEMM1 out hi (frag)
    unsigned short* hb0 = (unsigned short*)alloc((size_t)N * 128 * 2);  // GEMM2 out row-major
    unsigned short* yb  = (unsigned short*)alloc((size_t)N * 128 * 2);  // tfm out (gather src)
    unsigned short* xb  = (unsigned short*)alloc((size_t)N * 48 * 2);
    unsigned* row_ptr = (unsigned*)alloc((size_t)(N + 1) * 4);
    unsigned* colb    = (unsigned*)alloc((size_t)E * 4);
    unsigned* pair    = (unsigned*)alloc((size_t)E * 4);
    unsigned* cntm    = (unsigned*)alloc((size_t)NPART * NBUCKET * 4);
    unsigned* btot    = (unsigned*)alloc((size_t)(NBUCKET + 1) * 4);
    unsigned* bbase   = (unsigned*)alloc((size_t)(NBUCKET + 1) * 4);
    unsigned* gptr    = (unsigned*)alloc((size_t)(G + 1) * 4);
    unsigned short* wt = (unsigned short*)alloc((size_t)8 * 32768 * 2);
    float*    statsZ  = (float*)alloc(7 * 256 * 4);
    auto gnstats = [&](int i) { return statsZ + (size_t)i * 256; };
    auto pnstats = [&](int i) { return statsZ + (size_t)(4 + i) * 256; };

    hipMemsetAsync(statsZ, 0, 7 * 256 * 4, stream);

    // CSR build (no global atomics): phist -> btot -> scan -> poff -> pscat -> fillc2
    phist_kernel<<<NPART, 256, 0, stream>>>(ei + E, cntm, E, CHUNK);
    btot_kernel<<<(NBUCKET + 255) / 256, 256, 0, stream>>>(cntm, btot);
    scan_kernel<<<1, 1024, 0, stream>>>(btot, bbase, NBUCKET);
    poff_kernel<<<(NBUCKET + 3) / 4, 256, 0, stream>>>(cntm, bbase);
    pscat_kernel<<<NPART, 256, 0, stream>>>(ei, cntm, pair, E, CHUNK);
    fillc2_kernel<<<NBUCKET, 256, 0, stream>>>(pair, bbase, row_ptr, colb, N);
    gsearch_kernel<<<(G + 256) / 256, 256, 0, stream>>>(batch, gptr, N, G);
    wsplit_kernel<<<dim3(128, 8), 256, 0, stream>>>(W1_0, W1_rest, W2, wt);
    cast_kernel<<<(N * 48 / 4 + 255) / 256, 256, 0, stream>>>(x, xb, N * 48 / 4);

    const float invN = 1.f / (float)N;
    int gemm_grid = (N + 191) / 192;
    int agg_grid  = (N + 3) / 4;
    int tfm_grid  = (N * 16 + 255) / 256;

    // ---- layer 0 (K=48 padded to 64, KOCT=8 frag) ----
    agg_kernel<48, 8><<<agg_grid, 256, 0, stream>>>(xb, 48, row_ptr, colb, p1h, N);
    mgemm_kernel<2, 8, false, true, false, true><<<gemm_grid, 256, 0, stream>>>(
            p1h, nullptr, nullptr, nullptr, nullptr, invN,
            wt, b1_0, nullptr, p2h, gnstats(0), N);
    mgemm_kernel<4, 16, true, true, true, false><<<gemm_grid, 256, 0, stream>>>(
            p2h, gnstats(0), gn_w, gn_b, gn_s, invN,
            wt + 1 * 32768, b2, hb0, nullptr, pnstats(0), N);

    // ---- layers 1..3 ----
    for (int i = 1; i < 4; ++i) {
        tfm_kernel<<<tfm_grid, 256, 0, stream>>>(hb0, pnstats(i - 1),
                pn_w + (i - 1) * 128, pn_b + (i - 1) * 128, pn_s + (i - 1) * 128, invN,
                yb, N * 16);
        agg_kernel<128, 16><<<agg_grid, 256, 0, stream>>>(yb, 128, row_ptr, colb, p1h, N);
        mgemm_kernel<4, 16, false, true, false, true><<<gemm_grid, 256, 0, stream>>>(
                p1h, nullptr, nullptr, nullptr, nullptr, invN,
                wt + (size_t)(2 * i) * 32768, b1_rest + (size_t)(i - 1) * 128,
                nullptr, p2h, gnstats(i), N);
        if (i < 3) {
            mgemm_kernel<4, 16, true, true, true, false><<<gemm_grid, 256, 0, stream>>>(
                    p2h, gnstats(i), gn_w + i * 128, gn_b + i * 128, gn_s + i * 128, invN,
                    wt + (size_t)(2 * i + 1) * 32768, b2 + (size_t)i * 128,
                    hb0, nullptr, pnstats(i), N);
        } else {
            mgemm_kernel<4, 16, true, false, true, false><<<gemm_grid, 256, 0, stream>>>(
                    p2h, gnstats(3), gn_w + 3 * 128, gn_b + 3 * 128, gn_s + 3 * 128, invN,
                    wt + (size_t)7 * 32768, b2 + (size_t)3 * 128,
                    hb0, nullptr, nullptr, N);
        }
    }

    poolhead_kernel<<<G, 64, 0, stream>>>(hb0, gptr, fc1W, fc1b, fc2W, fc2b, outp, G);
}

// Round 16
// 699.067 us; speedup vs baseline: 1.0165x; 1.0165x over previous
//
#include <hip/hip_runtime.h>
#include <hip/hip_bf16.h>
#include <math.h>

#define N_NODES  100000
#define N_EDGES  1600000
#define N_GRAPHS 4096
#define NBUCKET  ((N_NODES + 127) / 128)   // 782
#define NPART    256
#define ROWBLKS_AL 6256                    // padded 16-row blocks for OOB-safe frag reads

typedef __attribute__((ext_vector_type(4))) float f32x4;
typedef __attribute__((ext_vector_type(8))) short bf16x8;

__device__ __forceinline__ float lrelu(float x) { return fmaxf(x, 0.01f * x); }

__device__ __forceinline__ unsigned short f2bf(float f) {
    unsigned u = __float_as_uint(f);
    unsigned r = (u + 0x7FFFu + ((u >> 16) & 1u)) >> 16;
    return (unsigned short)r;
}
__device__ __forceinline__ float bf2f(unsigned short h) {
    return __uint_as_float(((unsigned)h) << 16);
}

// ------- exclusive scan, single block 1024 thr, shuffle-based --------------
__global__ __launch_bounds__(1024) void scan_kernel(const unsigned* __restrict__ in,
                                                    unsigned* __restrict__ out, int n) {
    __shared__ unsigned wsum[16];
    __shared__ unsigned carry_s;
    int t = threadIdx.x, lane = t & 63, wv = t >> 6;
    if (t == 0) carry_s = 0u;
    __syncthreads();
    for (int base = 0; base < n; base += 4096) {
        unsigned carry = carry_s;
        unsigned v[4]; unsigned s = 0u;
#pragma unroll
        for (int i = 0; i < 4; ++i) {
            int idx = base + t * 4 + i;
            v[i] = (idx < n) ? in[idx] : 0u;
            s += v[i];
        }
        unsigned ps = s;
#pragma unroll
        for (int off = 1; off < 64; off <<= 1) {
            unsigned x = __shfl_up(ps, off, 64);
            if (lane >= off) ps += x;
        }
        if (lane == 63) wsum[wv] = ps;
        __syncthreads();
        if (wv == 0 && lane < 16) {
            unsigned pw = wsum[lane];
#pragma unroll
            for (int off = 1; off < 16; off <<= 1) {
                unsigned x = __shfl_up(pw, off, 64);
                if (lane >= off) pw += x;
            }
            wsum[lane] = pw;
        }
        __syncthreads();
        unsigned wbase = wv ? wsum[wv - 1] : 0u;
        unsigned run = carry + wbase + (ps - s);
#pragma unroll
        for (int i = 0; i < 4; ++i) {
            int idx = base + t * 4 + i;
            if (idx < n) out[idx] = run;
            run += v[i];
        }
        unsigned total = wsum[15];
        __syncthreads();
        if (t == 0) carry_s = carry + total;
        __syncthreads();
    }
    if (t == 0) out[n] = carry_s;
}

// ---- CSR pass 1: per-partition bucket histogram (LDS only) ----------------
__global__ __launch_bounds__(256) void phist_kernel(const int* __restrict__ dst,
        unsigned* __restrict__ cnt, int E, int chunk) {
    __shared__ unsigned lc[NBUCKET];
    int p = blockIdx.x, t = threadIdx.x;
    for (int i = t; i < NBUCKET; i += 256) lc[i] = 0u;
    __syncthreads();
    int e0 = p * chunk, e1 = e0 + chunk; if (e1 > E) e1 = E;
    for (int e = e0 + t; e < e1; e += 256)
        atomicAdd(&lc[((unsigned)dst[e]) >> 7], 1u);
    __syncthreads();
    for (int i = t; i < NBUCKET; i += 256) cnt[(size_t)p * NBUCKET + i] = lc[i];
}

// ---- CSR pass 1b: bucket totals (column sums of cnt[p][b]) ----------------
__global__ void btot_kernel(const unsigned* __restrict__ cnt, unsigned* __restrict__ tot) {
    int b = blockIdx.x * 256 + threadIdx.x;
    if (b >= NBUCKET) return;
    unsigned s = 0u;
    for (int p = 0; p < NPART; ++p) s += cnt[(size_t)p * NBUCKET + b];
    tot[b] = s;
}

// ---- CSR pass 2a: per-bucket exclusive scan over partitions ---------------
__global__ __launch_bounds__(256) void poff_kernel(unsigned* __restrict__ cnt,
        const unsigned* __restrict__ bucket_base) {
    int b = blockIdx.x * 4 + (threadIdx.x >> 6);
    if (b >= NBUCKET) return;
    int lane = threadIdx.x & 63;
    unsigned v[4]; unsigned s = 0u;
#pragma unroll
    for (int i = 0; i < 4; ++i) {
        int p = lane * 4 + i;
        v[i] = cnt[(size_t)p * NBUCKET + b];
        s += v[i];
    }
    unsigned ps = s;
#pragma unroll
    for (int off = 1; off < 64; off <<= 1) {
        unsigned x = __shfl_up(ps, off, 64);
        if (lane >= off) ps += x;
    }
    unsigned run = bucket_base[b] + (ps - s);
#pragma unroll
    for (int i = 0; i < 4; ++i) {
        int p = lane * 4 + i;
        cnt[(size_t)p * NBUCKET + b] = run;
        run += v[i];
    }
}

// ---- CSR pass 2b: scatter packed (src | dstLow<<20), LDS cursors ----------
__global__ __launch_bounds__(256) void pscat_kernel(const int* __restrict__ ei,
        const unsigned* __restrict__ cnt, unsigned* __restrict__ pair, int E, int chunk) {
    __shared__ unsigned lcur[NBUCKET];
    int p = blockIdx.x, t = threadIdx.x;
    for (int i = t; i < NBUCKET; i += 256) lcur[i] = cnt[(size_t)p * NBUCKET + i];
    __syncthreads();
    int e0 = p * chunk, e1 = e0 + chunk; if (e1 > E) e1 = E;
    for (int e = e0 + t; e < e1; e += 256) {
        unsigned src = (unsigned)ei[e];
        unsigned dst = (unsigned)ei[E + e];
        unsigned b = dst >> 7;
        unsigned pos = atomicAdd(&lcur[b], 1u);
        pair[pos] = src | ((dst & 127u) << 20);
    }
}

// ---- CSR pass 3: per-bucket degree count + LDS scan -> row_ptr, fine sort -> col
__global__ __launch_bounds__(256) void fillc2_kernel(const unsigned* __restrict__ pair,
        const unsigned* __restrict__ bucket_base, unsigned* __restrict__ row_ptr,
        unsigned* __restrict__ col, int N) {
    __shared__ unsigned lcnt[128], lpre[128], lcur[128];
    int b = blockIdx.x;
    int node0 = b << 7;
    int t = threadIdx.x;
    if (t < 128) { lcnt[t] = 0u; lcur[t] = 0u; }
    __syncthreads();
    unsigned bb = bucket_base[b], be = bucket_base[b + 1];
    for (unsigned i = bb + t; i < be; i += 256)
        atomicAdd(&lcnt[(pair[i] >> 20) & 127u], 1u);
    __syncthreads();
    if (t < 64) {
        unsigned v0 = lcnt[2 * t], v1 = lcnt[2 * t + 1];
        unsigned s = v0 + v1;
        unsigned ps = s;
#pragma unroll
        for (int off = 1; off < 64; off <<= 1) {
            unsigned x = __shfl_up(ps, off, 64);
            if (t >= off) ps += x;
        }
        unsigned base = ps - s;
        lpre[2 * t] = base;
        lpre[2 * t + 1] = base + v0;
    }
    __syncthreads();
    if (t < 128) {
        int node = node0 + t;
        if (node < N) row_ptr[node] = bb + lpre[t];
    }
    if (b == (int)gridDim.x - 1 && t == 0) row_ptr[N] = be;
    for (unsigned i = bb + t; i < be; i += 256) {
        unsigned u = pair[i];
        unsigned d = (u >> 20) & 127u;
        unsigned pos = bb + lpre[d] + atomicAdd(&lcur[d], 1u);
        col[pos] = u & 0xFFFFFu;
    }
}

// ---- graph segmentation: batch is sorted -> binary search per boundary ----
__global__ void gsearch_kernel(const int* __restrict__ batch, unsigned* __restrict__ gptr,
                               int N, int G) {
    int g = blockIdx.x * 256 + threadIdx.x;
    if (g > G) return;
    int lo = 0, hi = N;
    while (lo < hi) { int mid = (lo + hi) >> 1; if (batch[mid] < g) lo = mid + 1; else hi = mid; }
    gptr[g] = (unsigned)lo;
}

// ---------------- cast x (f32) -> bf16 shadow, x4 vectorized ---------------
__global__ void cast_kernel(const float* __restrict__ in, unsigned short* __restrict__ outb, int n4) {
    int i = blockIdx.x * 256 + threadIdx.x;
    if (i >= n4) return;
    f32x4 v = *(const f32x4*)(in + (size_t)i * 4);
    uint2 u;
    u.x = (unsigned)f2bf(v[0]) | ((unsigned)f2bf(v[1]) << 16);
    u.y = (unsigned)f2bf(v[2]) | ((unsigned)f2bf(v[3]) << 16);
    *(uint2*)(outb + (size_t)i * 4) = u;
}

// ---- transform pass: y = lrelu(a*h + d), affine from stats (LDS) ---------
__global__ __launch_bounds__(256) void tfm_kernel(const unsigned short* __restrict__ hb,
        const float* __restrict__ stats, const float* __restrict__ wp,
        const float* __restrict__ bp, const float* __restrict__ sp, float invN,
        unsigned short* __restrict__ yb, int total8) {
    __shared__ float la[128], ldd[128];
    int t = threadIdx.x;
    if (t < 128) {
        float mean = stats[t] * invN;
        float ex2  = stats[128 + t] * invN;
        float sv   = sp[t];
        float var  = ex2 - 2.f * sv * mean * mean + sv * sv * mean * mean;
        float a    = wp[t] * rsqrtf(var + 1e-5f);
        la[t] = a; ldd[t] = bp[t] - a * sv * mean;
    }
    __syncthreads();
    int i = blockIdx.x * 256 + t;
    if (i >= total8) return;
    int c0 = (i & 15) * 8;
    uint4 u = *(const uint4*)(hb + (size_t)i * 8);
    unsigned uu[4] = {u.x, u.y, u.z, u.w};
    unsigned ow[4];
#pragma unroll
    for (int q = 0; q < 4; ++q) {
        int c = c0 + 2 * q;
        float v0 = lrelu(fmaf(la[c],     __uint_as_float(uu[q] << 16),         ldd[c]));
        float v1 = lrelu(fmaf(la[c + 1], __uint_as_float(uu[q] & 0xffff0000u), ldd[c + 1]));
        ow[q] = (unsigned)f2bf(v0) | ((unsigned)f2bf(v1) << 16);
    }
    uint4 o; o.x = ow[0]; o.y = ow[1]; o.z = ow[2]; o.w = ow[3];
    *(uint4*)(yb + (size_t)i * 8) = o;
}

// ---------------- aggregation: m[n] = y[n] + sum_{j in N(n)} y[j] ----------
// pure sum; one wave per node (64 lanes x 4B = 256B per edge row); 8-deep
// edge unroll -> 2KB in flight/wave; writes MFMA-fragment-linear layout.
template<int D, int KOCT>
__global__ __launch_bounds__(256) void agg_kernel(const unsigned short* __restrict__ hb, int ld_in,
        const unsigned* __restrict__ row_ptr, const unsigned* __restrict__ col,
        unsigned short* __restrict__ op, int n) {
    int node = blockIdx.x * 4 + (threadIdx.x >> 6);
    int l = threadIdx.x & 63;
    if (node >= n || l >= KOCT * 4) return;
    int c = 2 * l;
    float x0 = 0.f, x1 = 0.f;
    if (c < D) {
        const unsigned short* hp = hb + c;
#define LOADU(s) *(const unsigned*)(hp + (size_t)(s) * ld_in)
#define LO(u) __uint_as_float((u) << 16)
#define HI(u) __uint_as_float((u) & 0xffff0000u)
        unsigned su = LOADU(node);
        x0 = LO(su); x1 = HI(su);
        float y0 = 0.f, y1 = 0.f, z0 = 0.f, z1 = 0.f, q0 = 0.f, q1 = 0.f;
        unsigned e0 = row_ptr[node], e1 = row_ptr[node + 1];
        unsigned e = e0;
        for (; e + 8 <= e1; e += 8) {
            unsigned c0i = col[e],     c1i = col[e + 1], c2i = col[e + 2], c3i = col[e + 3];
            unsigned c4i = col[e + 4], c5i = col[e + 5], c6i = col[e + 6], c7i = col[e + 7];
            unsigned u0 = LOADU(c0i), u1 = LOADU(c1i), u2 = LOADU(c2i), u3 = LOADU(c3i);
            unsigned u4 = LOADU(c4i), u5 = LOADU(c5i), u6 = LOADU(c6i), u7 = LOADU(c7i);
            x0 += LO(u0); x1 += HI(u0); y0 += LO(u1); y1 += HI(u1);
            z0 += LO(u2); z1 += HI(u2); q0 += LO(u3); q1 += HI(u3);
            x0 += LO(u4); x1 += HI(u4); y0 += LO(u5); y1 += HI(u5);
            z0 += LO(u6); z1 += HI(u6); q0 += LO(u7); q1 += HI(u7);
        }
        for (; e + 4 <= e1; e += 4) {
            unsigned c0i = col[e], c1i = col[e + 1], c2i = col[e + 2], c3i = col[e + 3];
            unsigned u0 = LOADU(c0i), u1 = LOADU(c1i), u2 = LOADU(c2i), u3 = LOADU(c3i);
            x0 += LO(u0); x1 += HI(u0); y0 += LO(u1); y1 += HI(u1);
            z0 += LO(u2); z1 += HI(u2); q0 += LO(u3); q1 += HI(u3);
        }
        for (; e < e1; ++e) {
            unsigned u = LOADU(col[e]);
            x0 += LO(u); x1 += HI(u);
        }
#undef LOADU
#undef LO
#undef HI
        x0 = (x0 + y0) + (z0 + q0);
        x1 = (x1 + y1) + (z1 + q1);
    }
    unsigned outw = (unsigned)f2bf(x0) | ((unsigned)f2bf(x1) << 16);
    size_t fo = (((size_t)(node >> 4) * KOCT + (l >> 2)) * 16 + (node & 15)) * 8 + 2 * (l & 3);
    *(unsigned*)(op + fo) = outw;
}

// ---- W preprocess: hi/lo bf16 split into FRAGMENT-LINEAR order -----------
__global__ __launch_bounds__(256) void wsplit_kernel(const float* __restrict__ W1_0,
        const float* __restrict__ W1_rest, const float* __restrict__ W2,
        unsigned short* __restrict__ wt) {
    int g = blockIdx.y;
    int i = blockIdx.x * 256 + threadIdx.x;   // i < 32768
    int e = i & 7, lane = (i >> 3) & 63, h = (i >> 9) & 1, j = (i >> 10) & 7, ks = i >> 13;
    int m = lane & 15, kg = lane >> 4;
    int k = ks * 32 + kg * 8 + e;
    int n = 8 * m + j;
    float v = 0.f;
    if (g == 0) { if (k < 48) v = W1_0[k * 128 + n]; }
    else if (g & 1) v = W2[(size_t)((g - 1) >> 1) * 16384 + k * 128 + n];
    else            v = W1_rest[(size_t)((g - 2) >> 1) * 16384 + k * 128 + n];
    unsigned short hi = f2bf(v);
    unsigned short out = (h == 0) ? hi : f2bf(v - bf2f(hi));
    wt[(size_t)g * 32768 + i] = out;
}

// ---------------- MFMA GEMM v8b (round-14 best) ---------------------------
// block = 4 waves (2x2): wave = 64 rows (4 rowgroups) x 64 cols.
// __launch_bounds__(256,3): 3 blocks/CU (12 waves) for latency hiding.
template<int KS, int KOCT, bool AFF, bool STATS, bool BF16OUT, bool FRAGOUT>
__global__ __launch_bounds__(256, 3) void mgemm_kernel(
        const unsigned short* __restrict__ Ah,
        const float* __restrict__ stats, const float* __restrict__ wp,
        const float* __restrict__ bp, const float* __restrict__ sp, float invN,
        const unsigned short* __restrict__ Wt, const float* __restrict__ bias,
        unsigned short* __restrict__ outb, unsigned short* __restrict__ ofh,
        float* __restrict__ ostats, int M) {
    __shared__ float ls[256];
    int t = threadIdx.x;
    if (STATS) { ls[t] = 0.f; __syncthreads(); }
    int lane = t & 63;
    int m = lane & 15, kg = lane >> 4;
    int wid = t >> 6;
    int wr = wid >> 1, wc = wid & 1;
    int rowBase = blockIdx.x * 128 + wr * 64;
    int rowblk0 = blockIdx.x * 8 + wr * 4;

    union U8 { bf16x8 v; unsigned short u[8]; };

    f32x4 acc[4][4];
#pragma unroll
    for (int j = 0; j < 4; ++j) {
        float b = bias[8 * m + wc * 4 + j];
#pragma unroll
        for (int rg = 0; rg < 4; ++rg) acc[rg][j] = (f32x4){b, b, b, b};
    }

#pragma unroll
    for (int ks = 0; ks < KS; ++ks) {
        int k0 = ks * 32 + kg * 8;
        float aC[8], dC[8];
        if (AFF) {
            f32x4 sm0 = *(const f32x4*)(stats + k0),       sm1 = *(const f32x4*)(stats + k0 + 4);
            f32x4 se0 = *(const f32x4*)(stats + 128 + k0), se1 = *(const f32x4*)(stats + 128 + k0 + 4);
            f32x4 w0  = *(const f32x4*)(wp + k0),          w1  = *(const f32x4*)(wp + k0 + 4);
            f32x4 b0  = *(const f32x4*)(bp + k0),          b1  = *(const f32x4*)(bp + k0 + 4);
            f32x4 s0  = *(const f32x4*)(sp + k0),          s1  = *(const f32x4*)(sp + k0 + 4);
#pragma unroll
            for (int q = 0; q < 8; ++q) {
                float mean = (q < 4 ? sm0[q] : sm1[q - 4]) * invN;
                float ex2  = (q < 4 ? se0[q] : se1[q - 4]) * invN;
                float sv   = (q < 4 ? s0[q]  : s1[q - 4]);
                float var  = ex2 - 2.f * sv * mean * mean + sv * sv * mean * mean;
                float a    = (q < 4 ? w0[q] : w1[q - 4]) * rsqrtf(var + 1e-5f);
                aC[q] = a;
                dC[q] = (q < 4 ? b0[q] : b1[q - 4]) - a * sv * mean;
            }
        }
        U8 fh[4];
#pragma unroll
        for (int rg = 0; rg < 4; ++rg) {
            size_t ao = (((size_t)(rowblk0 + rg) * KOCT + ks * 4 + kg) << 7) + (m << 3);
            U8 h;
            h.v = *(const bf16x8*)(Ah + ao);          // in-bounds by padded alloc
            if (AFF) {
#pragma unroll
                for (int q = 0; q < 8; ++q) {
                    float xv = lrelu(fmaf(aC[q], bf2f(h.u[q]), dC[q]));
                    h.u[q] = f2bf(xv);
                }
            }
            fh[rg] = h;
        }
#pragma unroll
        for (int j = 0; j < 4; ++j) {
            size_t wo = (size_t)(ks * 8 + wc * 4 + j) * 1024 + (size_t)lane * 8;
            bf16x8 whi = *(const bf16x8*)(Wt + wo);
            bf16x8 wlo = *(const bf16x8*)(Wt + wo + 512);
#pragma unroll
            for (int rg = 0; rg < 4; ++rg) {
                acc[rg][j] = __builtin_amdgcn_mfma_f32_16x16x32_bf16(fh[rg].v, whi, acc[rg][j], 0, 0, 0);
                acc[rg][j] = __builtin_amdgcn_mfma_f32_16x16x32_bf16(fh[rg].v, wlo, acc[rg][j], 0, 0, 0);
            }
        }
    }

    // epilogue: row = rowBase + rg*16 + kg*4 + r; lane's cols = 8m+wc*4 .. +3
#pragma unroll
    for (int rg = 0; rg < 4; ++rg) {
#pragma unroll
        for (int r = 0; r < 4; ++r) {
            int gr = rowBase + rg * 16 + kg * 4 + r;
            if (gr < M) {
                unsigned short h[4];
#pragma unroll
                for (int q = 0; q < 4; ++q) h[q] = f2bf(acc[rg][q][r]);
                uint2 uh;
                uh.x = (unsigned)h[0] | ((unsigned)h[1] << 16);
                uh.y = (unsigned)h[2] | ((unsigned)h[3] << 16);
                if (BF16OUT) *(uint2*)(outb + (size_t)gr * 128 + 8 * m + wc * 4) = uh;
                if (FRAGOUT) {
                    size_t fo = (((size_t)(rowblk0 + rg) * 16 + m) * 16 + (kg * 4 + r)) * 8 + wc * 4;
                    *(uint2*)(ofh + fo) = uh;
                }
            }
        }
    }

    if (STATS) {
#pragma unroll
        for (int j = 0; j < 4; ++j) {
            float s = 0.f, s2 = 0.f;
#pragma unroll
            for (int rg = 0; rg < 4; ++rg)
#pragma unroll
                for (int r = 0; r < 4; ++r) {
                    int gr = rowBase + rg * 16 + kg * 4 + r;
                    if (gr < M) { float v = acc[rg][j][r]; s += v; s2 += v * v; }
                }
            atomicAdd(&ls[8 * m + wc * 4 + j], s);
            atomicAdd(&ls[128 + 8 * m + wc * 4 + j], s2);
        }
        __syncthreads();
        atomicAdd(&ostats[t], ls[t]);
    }
}

// ------- fused pooling (mean/sum/max) + readout head, 1 wave per graph -----
__global__ __launch_bounds__(64) void poolhead_kernel(const unsigned short* __restrict__ hb,
        const unsigned* __restrict__ gptr,
        const float* __restrict__ w1, const float* __restrict__ b1,
        const float* __restrict__ w2, const float* __restrict__ b2,
        float* __restrict__ out, int G) {
    __shared__ float red[384];
    __shared__ float y[64];
    int g = blockIdx.x, t = threadIdx.x;
    unsigned s = gptr[g], e = gptr[g + 1];
    int c = 2 * t;
    float sx = 0.f, sy = 0.f, mx = -INFINITY, my = -INFINITY;
    for (unsigned n = s; n < e; ++n) {
        unsigned u = *(const unsigned*)(hb + (size_t)n * 128 + c);
        float vx = __uint_as_float(u << 16);
        float vy = __uint_as_float(u & 0xffff0000u);
        sx += vx; sy += vy;
        mx = fmaxf(mx, vx); my = fmaxf(my, vy);
    }
    float cnt = (float)(e - s);
    float inv = 1.f / fmaxf(cnt, 1.f);
    if (e == s) { mx = 0.f; my = 0.f; }
    red[c] = sx * inv;   red[c + 1] = sy * inv;
    red[128 + c] = sx;   red[129 + c] = sy;
    red[256 + c] = mx;   red[257 + c] = my;
    __syncthreads();
    float acc = b1[t];
    for (int k = 0; k < 384; ++k) acc += red[k] * w1[(size_t)k * 64 + t];
    y[t] = lrelu(acc);
    __syncthreads();
    if (t < 3) {
        float o = b2[t];
        for (int k = 0; k < 64; ++k) o += y[k] * w2[k * 3 + t];
        out[(size_t)g * 3 + t] = o;
    }
}

extern "C" void kernel_launch(void* const* d_in, const int* in_sizes, int n_in,
                              void* d_out, int out_size, void* d_ws, size_t ws_size,
                              hipStream_t stream) {
    const float* x       = (const float*)d_in[0];
    const float* W1_0    = (const float*)d_in[2];
    const float* b1_0    = (const float*)d_in[3];
    const float* W1_rest = (const float*)d_in[4];
    const float* b1_rest = (const float*)d_in[5];
    const float* gn_w    = (const float*)d_in[6];
    const float* gn_b    = (const float*)d_in[7];
    const float* gn_s    = (const float*)d_in[8];
    const float* W2      = (const float*)d_in[9];
    const float* b2      = (const float*)d_in[10];
    const float* pn_w    = (const float*)d_in[11];
    const float* pn_b    = (const float*)d_in[12];
    const float* pn_s    = (const float*)d_in[13];
    const float* fc1W    = (const float*)d_in[14];
    const float* fc1b    = (const float*)d_in[15];
    const float* fc2W    = (const float*)d_in[16];
    const float* fc2b    = (const float*)d_in[17];
    const int*   ei      = (const int*)d_in[18];
    const int*   batch   = (const int*)d_in[19];
    float* outp = (float*)d_out;

    const int N = N_NODES, E = N_EDGES, G = N_GRAPHS;
    const int CHUNK = (E + NPART - 1) / NPART;
    const size_t FRAGSZ = (size_t)ROWBLKS_AL * 16 * 128;   // shorts per frag plane
    char* w = (char*)d_ws;
    auto alloc = [&](size_t bytes) -> char* {
        char* p = w; w += (bytes + 255) & ~(size_t)255; return p;
    };
    unsigned short* p1h = (unsigned short*)alloc(FRAGSZ * 2);           // agg out (frag)
    unsigned short* p2h = (unsigned short*)alloc(FRAGSZ * 2);           // GEMM1 out hi (frag)
    unsigned short* hb0 = (unsigned short*)alloc((size_t)N * 128 * 2);  // GEMM2 out row-major
    unsigned short* yb  = (unsigned short*)alloc((size_t)N * 128 * 2);  // tfm out (gather src)
    unsigned short* xb  = (unsigned short*)alloc((size_t)N * 48 * 2);
    unsigned* row_ptr = (unsigned*)alloc((size_t)(N + 1) * 4);
    unsigned* colb    = (unsigned*)alloc((size_t)E * 4);
    unsigned* pair    = (unsigned*)alloc((size_t)E * 4);
    unsigned* cntm    = (unsigned*)alloc((size_t)NPART * NBUCKET * 4);
    unsigned* btot    = (unsigned*)alloc((size_t)(NBUCKET + 1) * 4);
    unsigned* bbase   = (unsigned*)alloc((size_t)(NBUCKET + 1) * 4);
    unsigned* gptr    = (unsigned*)alloc((size_t)(G + 1) * 4);
    unsigned short* wt = (unsigned short*)alloc((size_t)8 * 32768 * 2);
    float*    statsZ  = (float*)alloc(7 * 256 * 4);
    auto gnstats = [&](int i) { return statsZ + (size_t)i * 256; };
    auto pnstats = [&](int i) { return statsZ + (size_t)(4 + i) * 256; };

    hipMemsetAsync(statsZ, 0, 7 * 256 * 4, stream);

    // CSR build (no global atomics): phist -> btot -> scan -> poff -> pscat -> fillc2
    phist_kernel<<<NPART, 256, 0, stream>>>(ei + E, cntm, E, CHUNK);
    btot_kernel<<<(NBUCKET + 255) / 256, 256, 0, stream>>>(cntm, btot);
    scan_kernel<<<1, 1024, 0, stream>>>(btot, bbase, NBUCKET);
    poff_kernel<<<(NBUCKET + 3) / 4, 256, 0, stream>>>(cntm, bbase);
    pscat_kernel<<<NPART, 256, 0, stream>>>(ei, cntm, pair, E, CHUNK);
    fillc2_kernel<<<NBUCKET, 256, 0, stream>>>(pair, bbase, row_ptr, colb, N);
    gsearch_kernel<<<(G + 256) / 256, 256, 0, stream>>>(batch, gptr, N, G);
    wsplit_kernel<<<dim3(128, 8), 256, 0, stream>>>(W1_0, W1_rest, W2, wt);
    cast_kernel<<<(N * 48 / 4 + 255) / 256, 256, 0, stream>>>(x, xb, N * 48 / 4);

    const float invN = 1.f / (float)N;
    int gemm_grid = (N + 127) / 128;
    int agg_grid  = (N + 3) / 4;
    int tfm_grid  = (N * 16 + 255) / 256;

    // ---- layer 0 (K=48 padded to 64, KOCT=8 frag) ----
    agg_kernel<48, 8><<<agg_grid, 256, 0, stream>>>(xb, 48, row_ptr, colb, p1h, N);
    mgemm_kernel<2, 8, false, true, false, true><<<gemm_grid, 256, 0, stream>>>(
            p1h, nullptr, nullptr, nullptr, nullptr, invN,
            wt, b1_0, nullptr, p2h, gnstats(0), N);
    mgemm_kernel<4, 16, true, true, true, false><<<gemm_grid, 256, 0, stream>>>(
            p2h, gnstats(0), gn_w, gn_b, gn_s, invN,
            wt + 1 * 32768, b2, hb0, nullptr, pnstats(0), N);

    // ---- layers 1..3 ----
    for (int i = 1; i < 4; ++i) {
        tfm_kernel<<<tfm_grid, 256, 0, stream>>>(hb0, pnstats(i - 1),
                pn_w + (i - 1) * 128, pn_b + (i - 1) * 128, pn_s + (i - 1) * 128, invN,
                yb, N * 16);
        agg_kernel<128, 16><<<agg_grid, 256, 0, stream>>>(yb, 128, row_ptr, colb, p1h, N);
        mgemm_kernel<4, 16, false, true, false, true><<<gemm_grid, 256, 0, stream>>>(
                p1h, nullptr, nullptr, nullptr, nullptr, invN,
                wt + (size_t)(2 * i) * 32768, b1_rest + (size_t)(i - 1) * 128,
                nullptr, p2h, gnstats(i), N);
        if (i < 3) {
            mgemm_kernel<4, 16, true, true, true, false><<<gemm_grid, 256, 0, stream>>>(
                    p2h, gnstats(i), gn_w + i * 128, gn_b + i * 128, gn_s + i * 128, invN,
                    wt + (size_t)(2 * i + 1) * 32768, b2 + (size_t)i * 128,
                    hb0, nullptr, pnstats(i), N);
        } else {
            mgemm_kernel<4, 16, true, false, true, false><<<gemm_grid, 256, 0, stream>>>(
                    p2h, gnstats(3), gn_w + 3 * 128, gn_b + 3 * 128, gn_s + 3 * 128, invN,
                    wt + (size_t)7 * 32768, b2 + (size_t)3 * 128,
                    hb0, nullptr, nullptr, N);
        }
    }

    poolhead_kernel<<<G, 64, 0, stream>>>(hb0, gptr, fc1W, fc1b, fc2W, fc2b, outp, G);
}